// Round 7
// baseline (1154.978 us; speedup 1.0000x reference)
//
#include <hip/hip_runtime.h>
#include <math.h>

// ---------------- device helpers ----------------

__device__ __forceinline__ float elu_f(float x) {
    return x > 0.f ? x : expm1f(x);
}

// ---------------- node MLP ----------------

__global__ void mlp_kernel(const float* __restrict__ x,
                           const float* __restrict__ A, const float* __restrict__ ab,
                           const float* __restrict__ B, const float* __restrict__ bb,
                           float* __restrict__ out, int n) {
    __shared__ float sA[23 * 23], sB[23 * 23], sa[23], sb[23];
    for (int t = threadIdx.x; t < 23 * 23; t += blockDim.x) { sA[t] = A[t]; sB[t] = B[t]; }
    if (threadIdx.x < 23) { sa[threadIdx.x] = ab[threadIdx.x]; sb[threadIdx.x] = bb[threadIdx.x]; }
    __syncthreads();
    int i = blockIdx.x * blockDim.x + threadIdx.x;
    if (i >= n) return;
    float xi[23], h1[23];
    #pragma unroll
    for (int j = 0; j < 23; j++) xi[j] = x[(size_t)i * 23 + j];
    #pragma unroll
    for (int o = 0; o < 23; o++) {
        float acc = sa[o];
        #pragma unroll
        for (int j = 0; j < 23; j++) acc = fmaf(xi[j], sA[j * 23 + o], acc);
        h1[o] = elu_f(acc);
    }
    #pragma unroll
    for (int o = 0; o < 23; o++) {
        float acc = sb[o];
        #pragma unroll
        for (int j = 0; j < 23; j++) acc = fmaf(h1[j], sB[j * 23 + o], acc);
        out[(size_t)i * 23 + o] = elu_f(acc);
    }
}

// ---------------- register-tiled multi-output projection (GEMM) ----------------
// mode 0: fp32 row-major [stride floats].
// mode 1/2: k-part / v-part of a lane-major interleaved fp32 kv row:
//   row layout (floats): lane block ln = [k_{ln,0..CPL-1}, v_{ln,0..CPL-1}], stride=2*HC.
__device__ __forceinline__ void store_val(int mode, int kvcpl, void* base, int stride,
                                          int g, int c, float val) {
    if (mode == 0) {
        ((float*)base)[(size_t)g * stride + c] = val;
    } else {
        int ln = c / kvcpl, slot = c - ln * kvcpl;
        size_t pos = (size_t)g * stride + (size_t)ln * (2 * kvcpl) + slot
                   + (mode == 2 ? kvcpl : 0);
        ((float*)base)[pos] = val;
    }
}

template<int IN, int Kc, int OUTW, int M, int TY, int KVCPL>
__global__ void proj_tiled_kernel(const float* __restrict__ in, int n,
    const float* __restrict__ W0, const float* __restrict__ b0, void* __restrict__ o0, int st0, int md0,
    const float* __restrict__ W1, const float* __restrict__ b1, void* __restrict__ o1, int st1, int md1,
    const float* __restrict__ W2, const float* __restrict__ b2, void* __restrict__ o2, int st2, int md2,
    const float* __restrict__ W3, const float* __restrict__ b3, void* __restrict__ o3, int st3, int md3) {
    constexpr int WTOT = M * OUTW;
    constexpr int CG   = WTOT / 8;
    constexpr int BN   = TY * 4;
    constexpr int SAW  = BN + 4;
    constexpr int NT   = CG * TY;
    static_assert(IN % Kc == 0, "Kc must divide IN");
    __shared__ float sA[Kc][SAW];
    __shared__ float sB[Kc][WTOT];

    const int tid = threadIdx.x;
    const int tx = tid % CG;
    const int ty = tid / CG;
    const int node0 = blockIdx.x * BN;

    const int colA = tx * 4;
    const int colB = WTOT / 2 + tx * 4;
    const int matA = colA / OUTW, ccA = colA % OUTW;
    const int matB = colB / OUTW, ccB = colB % OUTW;
    const float* bA = (matA == 0 ? b0 : matA == 1 ? b1 : matA == 2 ? b2 : b3);
    const float* bB = (matB == 0 ? b0 : matB == 1 ? b1 : matB == 2 ? b2 : b3);
    void* oA = (matA == 0 ? o0 : matA == 1 ? o1 : matA == 2 ? o2 : o3);
    void* oB = (matB == 0 ? o0 : matB == 1 ? o1 : matB == 2 ? o2 : o3);
    const int stA = (matA == 0 ? st0 : matA == 1 ? st1 : matA == 2 ? st2 : st3);
    const int stB = (matB == 0 ? st0 : matB == 1 ? st1 : matB == 2 ? st2 : st3);
    const int mdA = (matA == 0 ? md0 : matA == 1 ? md1 : matA == 2 ? md2 : md3);
    const int mdB = (matB == 0 ? md0 : matB == 1 ? md1 : matB == 2 ? md2 : md3);

    float acc[4][8];
    #pragma unroll
    for (int i = 0; i < 4; i++) {
        #pragma unroll
        for (int c = 0; c < 4; c++) { acc[i][c] = bA[ccA + c]; acc[i][4 + c] = bB[ccB + c]; }
    }

    for (int k0 = 0; k0 < IN; k0 += Kc) {
        for (int t = tid; t < Kc * BN; t += NT) {
            int j = t / BN, nn = t - j * BN;
            int g = node0 + nn;
            sA[j][nn] = (g < n) ? in[(size_t)g * IN + k0 + j] : 0.f;
        }
        for (int t = tid; t < Kc * WTOT; t += NT) {
            int j = t / WTOT, c = t - j * WTOT;
            int m = c / OUTW, cm = c - m * OUTW;
            const float* Wp = (m == 0 ? W0 : m == 1 ? W1 : m == 2 ? W2 : W3);
            sB[j][c] = Wp[(size_t)(k0 + j) * OUTW + cm];
        }
        __syncthreads();
        #pragma unroll 8
        for (int j = 0; j < Kc; j++) {
            float4 a  = *(const float4*)&sA[j][ty * 4];
            float4 v0 = *(const float4*)&sB[j][colA];
            float4 v1 = *(const float4*)&sB[j][colB];
            float av[4] = {a.x, a.y, a.z, a.w};
            float bv[8] = {v0.x, v0.y, v0.z, v0.w, v1.x, v1.y, v1.z, v1.w};
            #pragma unroll
            for (int i = 0; i < 4; i++)
                #pragma unroll
                for (int c = 0; c < 8; c++)
                    acc[i][c] = fmaf(av[i], bv[c], acc[i][c]);
        }
        __syncthreads();
    }

    #pragma unroll
    for (int i = 0; i < 4; i++) {
        int g = node0 + ty * 4 + i;
        if (g >= n) continue;
        #pragma unroll
        for (int c = 0; c < 4; c++) {
            store_val(mdA, KVCPL, oA, stA, g, ccA + c, acc[i][c]);
            store_val(mdB, KVCPL, oB, stB, g, ccB + c, acc[i][4 + c]);
        }
    }
}

// ---------------- CSR build ----------------

__global__ void zero2_kernel(int* __restrict__ a, int* __restrict__ b, int n) {
    int i = blockIdx.x * blockDim.x + threadIdx.x;
    if (i < n) { a[i] = 0; b[i] = 0; }
}

__global__ void count_kernel(const int* __restrict__ dst, int* __restrict__ cnt, int nE) {
    int e = blockIdx.x * blockDim.x + threadIdx.x;
    if (e < nE) atomicAdd(&cnt[dst[e]], 1);
}

__global__ void scan_block_kernel(int* __restrict__ cnt, int* __restrict__ bsum, int n) {
    __shared__ int sdat[256];
    int i = blockIdx.x * 256 + threadIdx.x;
    int v = (i < n) ? cnt[i] : 0;
    sdat[threadIdx.x] = v;
    __syncthreads();
    for (int off = 1; off < 256; off <<= 1) {
        int t = (threadIdx.x >= (unsigned)off) ? sdat[threadIdx.x - off] : 0;
        __syncthreads();
        sdat[threadIdx.x] += t;
        __syncthreads();
    }
    if (i < n) cnt[i] = sdat[threadIdx.x] - v;
    if (threadIdx.x == 255) bsum[blockIdx.x] = sdat[255];
}

__global__ void scan_bsum_kernel(int* __restrict__ bsum, int nb) {
    __shared__ int s[1024];
    int i = threadIdx.x;
    int v = (i < nb) ? bsum[i] : 0;
    s[i] = v;
    __syncthreads();
    for (int off = 1; off < 1024; off <<= 1) {
        int t = (i >= off) ? s[i - off] : 0;
        __syncthreads();
        s[i] += t;
        __syncthreads();
    }
    if (i < nb) bsum[i] = s[i] - v;
}

__global__ void finalize_rp_kernel(const int* __restrict__ cnt, const int* __restrict__ bsum,
                                   int* __restrict__ rp, int n, int nE) {
    int i = blockIdx.x * blockDim.x + threadIdx.x;
    if (i < n) rp[i] = cnt[i] + bsum[i >> 8];
    if (i == n) rp[n] = nE;
}

__global__ void scatter_kernel(const int* __restrict__ src, const int* __restrict__ dst,
                               const int* __restrict__ rp, int* __restrict__ cur,
                               int* __restrict__ srcS, int* __restrict__ eidS, int nE) {
    int e = blockIdx.x * blockDim.x + threadIdx.x;
    if (e >= nE) return;
    int d = dst[e];
    int pos = rp[d] + atomicAdd(&cur[d], 1);
    srcS[pos] = src[e];
    eidS[pos] = e;
}

// ---------------- fused TransformerConv (one wave per dst node) ----------------
// kv: lane-major interleaved fp32 [n][64][2*CPL]; skip pre-stored in out[].
template<int IN, int C, bool QMAT, bool DOELU>
__global__ void conv_fused_kernel(const float* __restrict__ feat,
                                  const float* __restrict__ Wq, const float* __restrict__ qb,
                                  const float* __restrict__ kv,
                                  const float* __restrict__ qmat,
                                  const float* __restrict__ ea, const float* __restrict__ We,
                                  const int* __restrict__ rp, const int* __restrict__ srcS,
                                  const int* __restrict__ eidS,
                                  float* __restrict__ out, int n, float scale) {
    constexpr int HC = 8 * C;
    constexpr int CPL = HC / 64;
    constexpr int KVROW = 2 * HC;         // floats per node row
    const int lane = threadIdx.x & 63;
    const int d = blockIdx.x * (blockDim.x >> 6) + (threadIdx.x >> 6);
    if (d >= n) return;
    const int ch0 = lane * CPL;

    float we[7][CPL];
    #pragma unroll
    for (int j = 0; j < 7; j++)
        #pragma unroll
        for (int c = 0; c < CPL; c++) we[j][c] = We[j * HC + ch0 + c];

    float* op = out + (size_t)d * HC + ch0;
    float sk[CPL], q[CPL];
    #pragma unroll
    for (int c = 0; c < CPL; c++) sk[c] = op[c];       // pre-stored skip
    if constexpr (QMAT) {
        const float* qp = qmat + (size_t)d * HC + ch0;
        #pragma unroll
        for (int c = 0; c < CPL; c++) q[c] = qp[c];
    } else {
        #pragma unroll
        for (int c = 0; c < CPL; c++) q[c] = qb[ch0 + c];
        const float* fd = feat + (size_t)d * IN;
        for (int j = 0; j < IN; j++) {
            float f = fd[j];
            #pragma unroll
            for (int c = 0; c < CPL; c++)
                q[c] = fmaf(f, Wq[(size_t)j * HC + ch0 + c], q[c]);
        }
    }

    float m = -INFINITY, l = 0.f, acc[CPL];
    #pragma unroll
    for (int c = 0; c < CPL; c++) acc[c] = 0.f;

    const int p0 = rp[d], p1 = rp[d + 1];
    if (p0 < p1) {
        auto loadkv = [&](int s, float* kc, float* vc) {
            const float* pb = kv + (size_t)s * KVROW + lane * (2 * CPL);
            if constexpr (CPL == 3) {
                float2 a = *(const float2*)(pb + 0);
                float2 b = *(const float2*)(pb + 2);
                float2 c = *(const float2*)(pb + 4);
                kc[0] = a.x; kc[1] = a.y; kc[2] = b.x;
                vc[0] = b.y; vc[1] = c.x; vc[2] = c.y;
            } else {
                float2 a = *(const float2*)pb;
                kc[0] = a.x; vc[0] = a.y;
            }
        };
        float kc[CPL], vc[CPL], ev[7];
        loadkv(srcS[p0], kc, vc);
        {
            const float* e0 = ea + (size_t)eidS[p0] * 7;
            #pragma unroll
            for (int j = 0; j < 7; j++) ev[j] = e0[j];
        }

        for (int p = p0; p < p1; p++) {
            float kn[CPL], vn[CPL], evn[7];
            if (p + 1 < p1) {                           // prefetch next edge
                loadkv(srcS[p + 1], kn, vn);
                const float* e1 = ea + (size_t)eidS[p + 1] * 7;
                #pragma unroll
                for (int j = 0; j < 7; j++) evn[j] = e1[j];
            }
            float part = 0.f, vv[CPL];
            #pragma unroll
            for (int c = 0; c < CPL; c++) {
                float ec = 0.f;
                #pragma unroll
                for (int j = 0; j < 7; j++) ec = fmaf(ev[j], we[j][c], ec);
                part = fmaf(q[c], kc[c] + ec, part);
                vv[c] = vc[c] + ec;
            }
            part += __shfl_xor(part, 1);
            part += __shfl_xor(part, 2);
            part += __shfl_xor(part, 4);
            float z = part * scale;
            float mn = fmaxf(m, z);
            float rs = expf(m - mn);
            float pw = expf(z - mn);
            l = l * rs + pw;
            #pragma unroll
            for (int c = 0; c < CPL; c++) acc[c] = fmaf(acc[c], rs, pw * vv[c]);
            m = mn;
            #pragma unroll
            for (int c = 0; c < CPL; c++) { kc[c] = kn[c]; vc[c] = vn[c]; }
            #pragma unroll
            for (int j = 0; j < 7; j++) ev[j] = evn[j];
        }
    }
    float invl = (l > 0.f) ? 1.f / l : 0.f;
    #pragma unroll
    for (int c = 0; c < CPL; c++) {
        float r = sk[c] + acc[c] * invl;
        op[c] = DOELU ? elu_f(r) : r;
    }
}

// ---------------- head ----------------
__global__ void head_kernel(const float* __restrict__ h, const float* __restrict__ W1,
                            const float* __restrict__ b1, const float* __restrict__ W2,
                            const float* __restrict__ b2, float* __restrict__ out, int n) {
    __shared__ float sW1[64 * 20], sb1[20], sW2[20], sb2;
    for (int t = threadIdx.x; t < 64 * 20; t += blockDim.x) sW1[t] = W1[t];
    if (threadIdx.x < 20) { sb1[threadIdx.x] = b1[threadIdx.x]; sW2[threadIdx.x] = W2[threadIdx.x]; }
    if (threadIdx.x == 0) sb2 = b2[0];
    __syncthreads();
    int i = blockIdx.x * blockDim.x + threadIdx.x;
    if (i >= n) return;
    float hv[64];
    const float* hp = h + (size_t)i * 64;
    #pragma unroll
    for (int j = 0; j < 64; j++) hv[j] = elu_f(hp[j]);
    float acc2 = sb2;
    for (int o = 0; o < 20; o++) {
        float a = sb1[o];
        #pragma unroll
        for (int j = 0; j < 64; j++) a = fmaf(hv[j], sW1[j * 20 + o], a);
        acc2 = fmaf(elu_f(a), sW2[o], acc2);
    }
    out[i] = acc2;
}

__global__ void zero_out_kernel(float* __restrict__ out, int n) {
    int i = blockIdx.x * blockDim.x + threadIdx.x;
    if (i < n) out[i] = 0.f;
}

// ---------------- launcher ----------------

extern "C" void kernel_launch(void* const* d_in, const int* in_sizes, int n_in,
                              void* d_out, int out_size, void* d_ws, size_t ws_size,
                              hipStream_t stream) {
    const float* x   = (const float*)d_in[0];
    const int*   ei  = (const int*)d_in[1];
    const float* ea  = (const float*)d_in[2];
    const float* Aw  = (const float*)d_in[3];
    const float* Ab  = (const float*)d_in[4];
    const float* Bw  = (const float*)d_in[5];
    const float* Bb  = (const float*)d_in[6];
    const float* q1w = (const float*)d_in[7];  const float* q1b = (const float*)d_in[8];
    const float* k1w = (const float*)d_in[9];  const float* k1b = (const float*)d_in[10];
    const float* v1w = (const float*)d_in[11]; const float* v1b = (const float*)d_in[12];
    const float* e1w = (const float*)d_in[13];
    const float* s1w = (const float*)d_in[14]; const float* s1b = (const float*)d_in[15];
    const float* q2w = (const float*)d_in[16]; const float* q2b = (const float*)d_in[17];
    const float* k2w = (const float*)d_in[18]; const float* k2b = (const float*)d_in[19];
    const float* v2w = (const float*)d_in[20]; const float* v2b = (const float*)d_in[21];
    const float* e2w = (const float*)d_in[22];
    const float* s2w = (const float*)d_in[23]; const float* s2b = (const float*)d_in[24];
    const float* l1w = (const float*)d_in[25]; const float* l1b = (const float*)d_in[26];
    const float* l2w = (const float*)d_in[27]; const float* l2b = (const float*)d_in[28];

    const int n  = in_sizes[0] / 23;
    const int nE = in_sizes[1] / 2;
    const int* src = ei;
    const int* dst = ei + nE;
    float* out = (float*)d_out;
    const int B = 256;
    const int nb = (n + 255) / 256;

    // ---- workspace layout (float units); total = 599n floats + ints = 247.2 MB ----
    size_t fl_h1 = ((size_t)n * 23 + 3) & ~(size_t)3;
    size_t fl_o1 = (size_t)n * 192;
    size_t fl_kv = (size_t)n * 384;   // kv1 fp32 interleaved; conv2 reuses: kv2(128n)+q2(64n)+o2(64n)
    size_t ints_total = ((size_t)n + 1) + n + n + 1024 + (size_t)nE + (size_t)nE;
    size_t need_bytes = (fl_h1 + fl_o1 + fl_kv) * 4 + ints_total * 4;

    if (ws_size < need_bytes || nb > 1024) {
        zero_out_kernel<<<(out_size + B - 1) / B, B, 0, stream>>>(out, out_size);
        return;
    }

    float* ws = (float*)d_ws;
    size_t off = 0;
    float* h1    = ws + off; off += fl_h1;
    float* o1    = ws + off; off += fl_o1;
    float* kvreg = ws + off; off += fl_kv;
    int* ip = (int*)(ws + off);
    int* rp   = ip; ip += (size_t)n + 1;
    int* cnt  = ip; ip += n;
    int* cur  = ip; ip += n;
    int* bsum = ip; ip += 1024;
    int* srcS = ip; ip += nE;
    int* eidS = ip; ip += nE;

    float* kv1   = kvreg;                          // n*384 floats interleaved
    float* kv2   = kvreg;                          // n*128 floats interleaved (reuse)
    float* q2buf = kvreg + (size_t)n * 128;        // n*64 f
    float* o2    = kvreg + (size_t)n * 192;        // n*64 f

    const float sc1 = 1.0f / sqrtf(24.0f);
    const float sc2 = 1.0f / sqrtf(8.0f);
    const float* np = nullptr;
    void* npv = nullptr;

    // ---- CSR build ----
    zero2_kernel<<<(n + B - 1) / B, B, 0, stream>>>(cnt, cur, n);
    count_kernel<<<(nE + B - 1) / B, B, 0, stream>>>(dst, cnt, nE);
    scan_block_kernel<<<nb, 256, 0, stream>>>(cnt, bsum, n);
    scan_bsum_kernel<<<1, 1024, 0, stream>>>(bsum, nb);
    finalize_rp_kernel<<<(n + 1 + B - 1) / B, B, 0, stream>>>(cnt, bsum, rp, n, nE);
    scatter_kernel<<<(nE + B - 1) / B, B, 0, stream>>>(src, dst, rp, cur, srcS, eidS, nE);

    // ---- node MLP ----
    mlp_kernel<<<(n + B - 1) / B, B, 0, stream>>>(x, Aw, Ab, Bw, Bb, h1, n);

    const int gproj = (n + 31) / 32;

    // ---- conv1: k,v -> interleaved kv1; skip -> o1; fused edge phase ----
    proj_tiled_kernel<23, 23, 192, 3, 8, 3><<<gproj, 576, 0, stream>>>(
        h1, n,
        k1w, k1b, (void*)kv1, 384, 1,
        v1w, v1b, (void*)kv1, 384, 2,
        s1w, s1b, (void*)o1, 192, 0,
        np, np, npv, 0, 0);
    conv_fused_kernel<23, 24, false, true><<<(n + 3) / 4, 256, 0, stream>>>(
        h1, q1w, q1b, kv1, np, ea, e1w, rp, srcS, eidS, o1, n, sc1);

    // ---- conv2: q->q2buf, k,v->interleaved kv2, skip->o2; fused edge phase ----
    proj_tiled_kernel<192, 32, 64, 4, 8, 1><<<gproj, 256, 0, stream>>>(
        o1, n,
        q2w, q2b, (void*)q2buf, 64, 0,
        k2w, k2b, (void*)kv2, 128, 1,
        v2w, v2b, (void*)kv2, 128, 2,
        s2w, s2b, (void*)o2, 64, 0);
    conv_fused_kernel<192, 8, true, false><<<(n + 3) / 4, 256, 0, stream>>>(
        o1, q2w, q2b, kv2, q2buf, ea, e2w, rp, srcS, eidS, o2, n, sc2);

    // ---- head ----
    head_kernel<<<(n + B - 1) / B, B, 0, stream>>>(o2, l1w, l1b, l2w, l2b, out, n);
}